// Round 7
// baseline (399.965 us; speedup 1.0000x reference)
//
#include <hip/hip_runtime.h>

#define TLEN 4096
#define DIM 1024
#define NHEAD 16
#define HDIM 64
#define QKV_COLS (3 * DIM)
#define QSCALE 0.125f
#define NCHUNK 2
#define SCHUNK (TLEN / NCHUNK)

typedef __attribute__((ext_vector_type(8))) short short8;   // 8 bf16 = 4 VGPR (MFMA A/B frag)
typedef __attribute__((ext_vector_type(4))) float f32x4;    // MFMA C/D frag

struct alignas(8) s4 { short v[4]; };

__device__ float g_Lsum[NHEAD];
__device__ float g_recipL[NHEAD];

__global__ void zeroL() {
    if (threadIdx.x < NHEAD) g_Lsum[threadIdx.x] = 0.0f;
}
__global__ void recipL() {
    if (threadIdx.x < NHEAD) g_recipL[threadIdx.x] = 1.0f / g_Lsum[threadIdx.x];
}

__device__ __forceinline__ unsigned bf16_rtne_bits(float x) {
    unsigned u = __float_as_uint(x);
    return (u + 0x7fffu + ((u >> 16) & 1u)) >> 16;
}

// fp32 -> bf16 (RTNE), vectorized; n4 = element count / 4.
__global__ __launch_bounds__(256) void conv_bf16(
    const float* __restrict__ src, short* __restrict__ dst, int n4)
{
    int i = blockIdx.x * 256 + threadIdx.x;
    if (i < n4) {
        float4 v = ((const float4*)src)[i];
        s4 o;
        o.v[0] = (short)bf16_rtne_bits(v.x);
        o.v[1] = (short)bf16_rtne_bits(v.y);
        o.v[2] = (short)bf16_rtne_bits(v.z);
        o.v[3] = (short)bf16_rtne_bits(v.w);
        ((s4*)dst)[i] = o;
    }
}

// W_out [1024,1024] -> bf16 with per-head 1/L folded in (k-group = k/64).
__global__ __launch_bounds__(256) void conv_wout(
    const float* __restrict__ src, short* __restrict__ dst)
{
    int i = blockIdx.x * 256 + threadIdx.x;   // over 1024*1024/4
    float s = g_recipL[(i & 255) >> 4];       // k = (i&255)*4; head = k>>6
    float4 v = ((const float4*)src)[i];
    s4 o;
    o.v[0] = (short)bf16_rtne_bits(v.x * s);
    o.v[1] = (short)bf16_rtne_bits(v.y * s);
    o.v[2] = (short)bf16_rtne_bits(v.z * s);
    o.v[3] = (short)bf16_rtne_bits(v.w * s);
    ((s4*)dst)[i] = o;
}

// V region of qkvb [s][2048 + h*64 + d] -> vtb[(h*64+d)*TLEN + s]  (bf16)
__global__ __launch_bounds__(256) void transpose_v(
    const short* __restrict__ qkvb, short* __restrict__ vtb)
{
    __shared__ short t[64][72];
    const int tid = threadIdx.x;
    const int s0 = blockIdx.x * 64;
    const int h  = blockIdx.y;
    const int lr  = tid >> 2;          // 0..63
    const int c16 = (tid & 3) * 16;    // 0,16,32,48

    uint4 a = *(const uint4*)(qkvb + (size_t)(s0 + lr) * QKV_COLS + 2 * DIM + h * HDIM + c16);
    uint4 b = *(const uint4*)(qkvb + (size_t)(s0 + lr) * QKV_COLS + 2 * DIM + h * HDIM + c16 + 8);
    const short* pa = (const short*)&a;
    const short* pb = (const short*)&b;
#pragma unroll
    for (int m = 0; m < 8; ++m) t[c16 + m][lr] = pa[m];
#pragma unroll
    for (int m = 0; m < 8; ++m) t[c16 + 8 + m][lr] = pb[m];
    __syncthreads();
    *(uint4*)(vtb + (size_t)(h * HDIM + lr) * TLEN + s0 + c16)     = *(const uint4*)&t[lr][c16];
    *(uint4*)(vtb + (size_t)(h * HDIM + lr) * TLEN + s0 + c16 + 8) = *(const uint4*)&t[lr][c16 + 8];
}

// attnb = bf16(part0 + part1); n4 = elements/4.
__global__ __launch_bounds__(256) void combine(
    const short* __restrict__ p0, const short* __restrict__ p1,
    short* __restrict__ dst, int n4)
{
    int i = blockIdx.x * 256 + threadIdx.x;
    if (i < n4) {
        s4 a = ((const s4*)p0)[i];
        s4 b = ((const s4*)p1)[i];
        s4 o;
#pragma unroll
        for (int m = 0; m < 4; ++m) {
            float fa = __uint_as_float(((unsigned)(unsigned short)a.v[m]) << 16);
            float fb = __uint_as_float(((unsigned)(unsigned short)b.v[m]) << 16);
            o.v[m] = (short)bf16_rtne_bits(fa + fb);
        }
        ((s4*)dst)[i] = o;
    }
}

// C = A @ B^T, bf16 MFMA. 128x128 tile, 4 waves 2x2, BK=32.
// SCALE_Q: multiply output cols n < DIM by QSCALE (pre-scales Q for attention).
template <bool OUT_BF16, bool SCALE_Q>
__global__ __launch_bounds__(256) void gemm_bt(
    const short* __restrict__ A, const short* __restrict__ B,
    void* __restrict__ Cout, int M, int N, int K)
{
    __shared__ short As[128][32];
    __shared__ short Bs[128][32];
    const int tid  = threadIdx.x;
    const int wv   = tid >> 6, lane = tid & 63;
    const int fr   = lane & 15, quad = lane >> 4;
    const int wm   = (wv >> 1) * 64, wn = (wv & 1) * 64;
    const int m0 = blockIdx.x * 128, n0 = blockIdx.y * 128;

    f32x4 acc[4][4] = {};

    for (int k0 = 0; k0 < K; k0 += 32) {
        __syncthreads();
#pragma unroll
        for (int c = tid; c < 512; c += 256) {
            int row = c >> 2, col = (c & 3) * 8;
            *(uint4*)&As[row][col] = *(const uint4*)(A + (size_t)(m0 + row) * K + k0 + col);
            *(uint4*)&Bs[row][col] = *(const uint4*)(B + (size_t)(n0 + row) * K + k0 + col);
        }
        __syncthreads();

        short8 af[4], bfr[4];
#pragma unroll
        for (int i = 0; i < 4; ++i) {
            af[i]  = *(const short8*)&As[wm + i * 16 + fr][quad * 8];
            bfr[i] = *(const short8*)&Bs[wn + i * 16 + fr][quad * 8];
        }
#pragma unroll
        for (int i = 0; i < 4; ++i)
#pragma unroll
            for (int j = 0; j < 4; ++j)
                acc[i][j] = __builtin_amdgcn_mfma_f32_16x16x32_bf16(af[i], bfr[j], acc[i][j], 0, 0, 0);
    }

    const float sc = (SCALE_Q && n0 < DIM) ? QSCALE : 1.0f;
#pragma unroll
    for (int i = 0; i < 4; ++i)
#pragma unroll
        for (int j = 0; j < 4; ++j)
#pragma unroll
            for (int r = 0; r < 4; ++r) {
                size_t off = (size_t)(m0 + wm + i * 16 + quad * 4 + r) * N + n0 + wn + j * 16 + fr;
                float v = acc[i][j][r] * sc;
                if (OUT_BF16)
                    ((short*)Cout)[off] = (short)bf16_rtne_bits(v);
                else
                    ((float*)Cout)[off] = v;
            }
}

// Barrier-free attention. One block per (128-row Q tile, head, s-chunk);
// 4 waves, each owns a 32-row t-strip, fully independent (no __syncthreads
// in the s-loop). K, Q, V^T fragments are loaded DIRECTLY from global as
// b128 (layouts are d- or s-contiguous); only P round-trips through
// wave-private LDS (C-layout -> B-frag quad shuffle).
// S^T = mfma(K, Q); P = trunc-bf16(exp(S)); O^T += mfma(V^T, P).
// Partial O (unnormalized) written per chunk; lsum sums truncated P.
__global__ __launch_bounds__(256) void attn_mfma(
    const short* __restrict__ qkvb, const short* __restrict__ vtb,
    short* __restrict__ part)
{
    __shared__ short Ps[128][72];
    __shared__ float red[256];

    const int tid = threadIdx.x;
    const int t0 = blockIdx.x * 128;
    const int h  = blockIdx.y;
    const int chunk = blockIdx.z;
    const int wv   = tid >> 6;
    const int lane = tid & 63;
    const int fr   = lane & 15;
    const int quad = lane >> 4;
    const int tb   = wv * 32;

    // Q fragments (B-operand) direct from global: [t=t0+tb+jt*16+fr][d=kh*32+quad*8..]
    short8 qf[2][2];
#pragma unroll
    for (int jt = 0; jt < 2; ++jt)
#pragma unroll
        for (int kh = 0; kh < 2; ++kh)
            qf[jt][kh] = *(const short8*)(qkvb +
                (size_t)(t0 + tb + jt * 16 + fr) * QKV_COLS + h * HDIM + kh * 32 + quad * 8);

    f32x4 oaccT[4][2] = {};   // [jd][jt], O^T[d][t]
    float lsum = 0.0f;

    const short* Vh = vtb + (size_t)h * HDIM * TLEN;   // rows: d, stride TLEN (s-contig)

    for (int s0 = chunk * SCHUNK; s0 < (chunk + 1) * SCHUNK; s0 += 64) {
        const short* Kb = qkvb + (size_t)s0 * QKV_COLS + DIM + h * HDIM;

        // ---- S^T = K.Q^T: A-frag K[s][d] direct global; C: (s=i*16+quad*4+r, t=tb+jt*16+fr)
#pragma unroll
        for (int i = 0; i < 4; ++i) {
            short8 ka0 = *(const short8*)(Kb + (size_t)(i * 16 + fr) * QKV_COLS + quad * 8);
            short8 ka1 = *(const short8*)(Kb + (size_t)(i * 16 + fr) * QKV_COLS + 32 + quad * 8);
#pragma unroll
            for (int jt = 0; jt < 2; ++jt) {
                f32x4 acc = {};
                acc = __builtin_amdgcn_mfma_f32_16x16x32_bf16(ka0, qf[jt][0], acc, 0, 0, 0);
                acc = __builtin_amdgcn_mfma_f32_16x16x32_bf16(ka1, qf[jt][1], acc, 0, 0, 0);
                unsigned u0 = __float_as_uint(__expf(acc[0]));
                unsigned u1 = __float_as_uint(__expf(acc[1]));
                unsigned u2 = __float_as_uint(__expf(acc[2]));
                unsigned u3 = __float_as_uint(__expf(acc[3]));
                lsum += __uint_as_float(u0 & 0xffff0000u);
                lsum += __uint_as_float(u1 & 0xffff0000u);
                lsum += __uint_as_float(u2 & 0xffff0000u);
                lsum += __uint_as_float(u3 & 0xffff0000u);
                uint2 pk;
                pk.x = (u0 >> 16) | (u1 & 0xffff0000u);
                pk.y = (u2 >> 16) | (u3 & 0xffff0000u);
                *(uint2*)&Ps[tb + jt * 16 + fr][i * 16 + quad * 4] = pk;
            }
        }
        // no barrier: each wave reads back only its own Ps rows (same-wave lgkmcnt)

        // ---- O^T += V^T.P: A-frag V^T[d][s] direct global, B-frag P from LDS
        short8 pb[2][2];
#pragma unroll
        for (int jt = 0; jt < 2; ++jt)
#pragma unroll
            for (int kh = 0; kh < 2; ++kh)
                pb[jt][kh] = *(const short8*)&Ps[tb + jt * 16 + fr][kh * 32 + quad * 8];
#pragma unroll
        for (int jd = 0; jd < 4; ++jd) {
            short8 va0 = *(const short8*)(Vh + (size_t)(jd * 16 + fr) * TLEN + s0 + quad * 8);
            short8 va1 = *(const short8*)(Vh + (size_t)(jd * 16 + fr) * TLEN + s0 + 32 + quad * 8);
#pragma unroll
            for (int jt = 0; jt < 2; ++jt) {
                oaccT[jd][jt] = __builtin_amdgcn_mfma_f32_16x16x32_bf16(va0, pb[jt][0], oaccT[jd][jt], 0, 0, 0);
                oaccT[jd][jt] = __builtin_amdgcn_mfma_f32_16x16x32_bf16(va1, pb[jt][1], oaccT[jd][jt], 0, 0, 0);
            }
        }
    }

    // ---- epilogue: O^T[d][t] -> part[chunk][t][h*64+d], bf16, b64 stores ----
    short* pc = part + (size_t)chunk * TLEN * DIM;
#pragma unroll
    for (int jt = 0; jt < 2; ++jt)
#pragma unroll
        for (int jd = 0; jd < 4; ++jd) {
            unsigned u0 = bf16_rtne_bits(oaccT[jd][jt][0]);
            unsigned u1 = bf16_rtne_bits(oaccT[jd][jt][1]);
            unsigned u2 = bf16_rtne_bits(oaccT[jd][jt][2]);
            unsigned u3 = bf16_rtne_bits(oaccT[jd][jt][3]);
            uint2 pk;
            pk.x = u0 | (u1 << 16);
            pk.y = u2 | (u3 << 16);
            *(uint2*)(pc + (size_t)(t0 + tb + jt * 16 + fr) * DIM + h * HDIM + jd * 16 + quad * 4) = pk;
        }

    // ---- block-reduce lsum, one atomic per block ----
    red[tid] = lsum;
    __syncthreads();
    for (int off = 128; off > 0; off >>= 1) {
        if (tid < off) red[tid] += red[tid + off];
        __syncthreads();
    }
    if (tid == 0) atomicAdd(&g_Lsum[h], red[0]);
}

extern "C" void kernel_launch(void* const* d_in, const int* in_sizes, int n_in,
                              void* d_out, int out_size, void* d_ws, size_t ws_size,
                              hipStream_t stream)
{
    const float* x     = (const float*)d_in[0];   // [4096, 1024]
    const float* W_in  = (const float*)d_in[1];   // [3072, 1024]
    const float* W_out = (const float*)d_in[2];   // [1024, 1024]
    float* out = (float*)d_out;                   // [4096, 1024] fp32

    char* ws = (char*)d_ws;
    short* xb    = (short*)(ws);                   //  8 MiB @ 0   (later: attnb)
    short* wib   = (short*)(ws + (8u << 20));      //  6 MiB @ 8M
    short* wob   = (short*)(ws + (14u << 20));     //  2 MiB @ 14M
    short* qkvb  = (short*)(ws + (16u << 20));     // 24 MiB @ 16M
    short* vtb   = (short*)(ws + (40u << 20));     //  8 MiB @ 40M
    short* part  = (short*)(ws + (48u << 20));     // 16 MiB @ 48M (2 chunks x 8 MiB)
    short* attnb = xb;                             // reuse dead xb region
    // total: exactly 64 MiB (proven safe in R3/R4)

    zeroL<<<1, 64, 0, stream>>>();

    conv_bf16<<<(TLEN * DIM / 4 + 255) / 256, 256, 0, stream>>>(x, xb, TLEN * DIM / 4);
    conv_bf16<<<(QKV_COLS * DIM / 4 + 255) / 256, 256, 0, stream>>>(W_in, wib, QKV_COLS * DIM / 4);

    // qkv = x @ W_in^T  (bf16 MFMA; Q columns pre-scaled by 0.125)
    gemm_bt<true, true><<<dim3(TLEN / 128, QKV_COLS / 128), 256, 0, stream>>>(
        xb, wib, qkvb, TLEN, QKV_COLS, DIM);

    transpose_v<<<dim3(TLEN / 64, NHEAD), 256, 0, stream>>>(qkvb, vtb);

    attn_mfma<<<dim3(TLEN / 128, NHEAD, NCHUNK), 256, 0, stream>>>(qkvb, vtb, part);

    recipL<<<1, 64, 0, stream>>>();
    conv_wout<<<(DIM * DIM / 4 + 255) / 256, 256, 0, stream>>>(W_out, wob);

    combine<<<(TLEN * DIM / 4 + 255) / 256, 256, 0, stream>>>(
        part, part + (size_t)TLEN * DIM, attnb, TLEN * DIM / 4);

    // out = attn' @ (W_out/L)^T  (bf16 MFMA, fp32 out)
    gemm_bt<false, false><<<dim3(TLEN / 128, DIM / 128), 256, 0, stream>>>(
        attnb, wob, out, TLEN, DIM, DIM);
}

// Round 8
// 272.112 us; speedup vs baseline: 1.4699x; 1.4699x over previous
//
#include <hip/hip_runtime.h>

#define TLEN 4096
#define DIM 1024
#define NHEAD 16
#define HDIM 64
#define QKV_COLS (3 * DIM)
#define QSCALE 0.125f
#define NCHUNK 2
#define SCHUNK (TLEN / NCHUNK)

typedef __attribute__((ext_vector_type(8))) short short8;   // 8 bf16 = 4 VGPR (MFMA A/B frag)
typedef __attribute__((ext_vector_type(4))) float f32x4;    // MFMA C/D frag

struct alignas(8) s4 { short v[4]; };

__device__ float g_Lsum[NHEAD];
__device__ float g_recipL[NHEAD];

__global__ void zeroL() {
    if (threadIdx.x < NHEAD) g_Lsum[threadIdx.x] = 0.0f;
}
__global__ void recipL() {
    if (threadIdx.x < NHEAD) g_recipL[threadIdx.x] = 1.0f / g_Lsum[threadIdx.x];
}

__device__ __forceinline__ unsigned bf16_rtne_bits(float x) {
    unsigned u = __float_as_uint(x);
    return (u + 0x7fffu + ((u >> 16) & 1u)) >> 16;
}

// fp32 -> bf16 (RTNE), vectorized; n4 = element count / 4.
__global__ __launch_bounds__(256) void conv_bf16(
    const float* __restrict__ src, short* __restrict__ dst, int n4)
{
    int i = blockIdx.x * 256 + threadIdx.x;
    if (i < n4) {
        float4 v = ((const float4*)src)[i];
        s4 o;
        o.v[0] = (short)bf16_rtne_bits(v.x);
        o.v[1] = (short)bf16_rtne_bits(v.y);
        o.v[2] = (short)bf16_rtne_bits(v.z);
        o.v[3] = (short)bf16_rtne_bits(v.w);
        ((s4*)dst)[i] = o;
    }
}

// W_out [1024,1024] -> bf16 with per-head 1/L folded in (k-group = k/64).
__global__ __launch_bounds__(256) void conv_wout(
    const float* __restrict__ src, short* __restrict__ dst)
{
    int i = blockIdx.x * 256 + threadIdx.x;   // over 1024*1024/4
    float s = g_recipL[(i & 255) >> 4];       // k = (i&255)*4; head = k>>6
    float4 v = ((const float4*)src)[i];
    s4 o;
    o.v[0] = (short)bf16_rtne_bits(v.x * s);
    o.v[1] = (short)bf16_rtne_bits(v.y * s);
    o.v[2] = (short)bf16_rtne_bits(v.z * s);
    o.v[3] = (short)bf16_rtne_bits(v.w * s);
    ((s4*)dst)[i] = o;
}

// attnb = bf16(part0 + part1); n4 = elements/4.
__global__ __launch_bounds__(256) void combine(
    const short* __restrict__ p0, const short* __restrict__ p1,
    short* __restrict__ dst, int n4)
{
    int i = blockIdx.x * 256 + threadIdx.x;
    if (i < n4) {
        s4 a = ((const s4*)p0)[i];
        s4 b = ((const s4*)p1)[i];
        s4 o;
#pragma unroll
        for (int m = 0; m < 4; ++m) {
            float fa = __uint_as_float(((unsigned)(unsigned short)a.v[m]) << 16);
            float fb = __uint_as_float(((unsigned)(unsigned short)b.v[m]) << 16);
            o.v[m] = (short)bf16_rtne_bits(fa + fb);
        }
        ((s4*)dst)[i] = o;
    }
}

// C = A @ B^T, bf16 MFMA. 128x128 tile, 4 waves 2x2, BK=32.
// SCALE_Q: multiply output cols n < DIM by QSCALE (pre-scales Q for attention).
template <bool OUT_BF16, bool SCALE_Q>
__global__ __launch_bounds__(256) void gemm_bt(
    const short* __restrict__ A, const short* __restrict__ B,
    void* __restrict__ Cout, int M, int N, int K)
{
    __shared__ short As[128][32];
    __shared__ short Bs[128][32];
    const int tid  = threadIdx.x;
    const int wv   = tid >> 6, lane = tid & 63;
    const int fr   = lane & 15, quad = lane >> 4;
    const int wm   = (wv >> 1) * 64, wn = (wv & 1) * 64;
    const int m0 = blockIdx.x * 128, n0 = blockIdx.y * 128;

    f32x4 acc[4][4] = {};

    for (int k0 = 0; k0 < K; k0 += 32) {
        __syncthreads();
#pragma unroll
        for (int c = tid; c < 512; c += 256) {
            int row = c >> 2, col = (c & 3) * 8;
            *(uint4*)&As[row][col] = *(const uint4*)(A + (size_t)(m0 + row) * K + k0 + col);
            *(uint4*)&Bs[row][col] = *(const uint4*)(B + (size_t)(n0 + row) * K + k0 + col);
        }
        __syncthreads();

        short8 af[4], bfr[4];
#pragma unroll
        for (int i = 0; i < 4; ++i) {
            af[i]  = *(const short8*)&As[wm + i * 16 + fr][quad * 8];
            bfr[i] = *(const short8*)&Bs[wn + i * 16 + fr][quad * 8];
        }
#pragma unroll
        for (int i = 0; i < 4; ++i)
#pragma unroll
            for (int j = 0; j < 4; ++j)
                acc[i][j] = __builtin_amdgcn_mfma_f32_16x16x32_bf16(af[i], bfr[j], acc[i][j], 0, 0, 0);
    }

    const float sc = (SCALE_Q && n0 < DIM) ? QSCALE : 1.0f;
#pragma unroll
    for (int i = 0; i < 4; ++i)
#pragma unroll
        for (int j = 0; j < 4; ++j)
#pragma unroll
            for (int r = 0; r < 4; ++r) {
                size_t off = (size_t)(m0 + wm + i * 16 + quad * 4 + r) * N + n0 + wn + j * 16 + fr;
                float v = acc[i][j][r] * sc;
                if (OUT_BF16)
                    ((short*)Cout)[off] = (short)bf16_rtne_bits(v);
                else
                    ((float*)Cout)[off] = v;
            }
}

// LDS-staged attention (R6 structure) + s-chunking for occupancy.
// One block per (128-row Q tile, head, s-chunk); 4 waves, each owns a
// 32-row t-strip. K/V staged in LDS (shared by all 4 waves — the R7
// direct-global variant quadrupled L1 traffic and regressed).
// S^T = mfma(K,Q) -> P s-consecutive per lane -> b64 LDS stores, no 3rd
// barrier (wave-private P rows). O^T = mfma(V^T, P) -> b64 global stores.
// Q pre-scaled by 0.125; P truncated to bf16, lsum sums truncated values.
__global__ __launch_bounds__(256) void attn_mfma(
    const short* __restrict__ qkvb, short* __restrict__ part)
{
    __shared__ short Ks[64][72];    // [s][d]
    __shared__ short Vt[64][72];    // [d][s]
    __shared__ short Ps[128][72];   // Q staged here first ([t][d]), then P [t][s]
    __shared__ float red[256];

    const int tid = threadIdx.x;
    const int t0 = blockIdx.x * 128;
    const int h  = blockIdx.y;
    const int chunk = blockIdx.z;
    const int lr  = tid >> 2;          // 0..63
    const int lc4 = (tid & 3) << 2;    // 0,4,8,12
    const int wv   = tid >> 6;
    const int lane = tid & 63;
    const int fr   = lane & 15;
    const int quad = lane >> 4;
    const int tb   = wv * 32;          // wave's t-strip base within the tile

    // ---- stage Q (128x64, already x0.125) into the Ps region ----
#pragma unroll
    for (int half = 0; half < 128; half += 64)
#pragma unroll
        for (int c0 = 0; c0 < HDIM; c0 += 16) {
            int d = c0 + lc4;
            *(s4*)&Ps[half + lr][d] =
                *(const s4*)(qkvb + (size_t)(t0 + half + lr) * QKV_COLS + h * HDIM + d);
        }
    __syncthreads();

    // Q fragments (B-operand): [t = tb+jt*16+fr][d = kh*32+quad*8 ..]
    short8 qf[2][2];
#pragma unroll
    for (int jt = 0; jt < 2; ++jt)
#pragma unroll
        for (int kh = 0; kh < 2; ++kh)
            qf[jt][kh] = *(const short8*)&Ps[tb + jt * 16 + fr][kh * 32 + quad * 8];

    f32x4 oaccT[4][2] = {};   // [jd][jt], O^T[d][t]
    float lsum = 0.0f;

    for (int s0 = chunk * SCHUNK; s0 < (chunk + 1) * SCHUNK; s0 += 64) {
        __syncthreads();   // prev-iter readers of Ks/Vt/Ps done (also guards qf preload)
#pragma unroll
        for (int c0 = 0; c0 < HDIM; c0 += 16) {
            int d = c0 + lc4;
            *(s4*)&Ks[lr][d] =
                *(const s4*)(qkvb + (size_t)(s0 + lr) * QKV_COLS + DIM + h * HDIM + d);
            s4 vv = *(const s4*)(qkvb + (size_t)(s0 + lr) * QKV_COLS + 2 * DIM + h * HDIM + d);
            Vt[d + 0][lr] = vv.v[0];
            Vt[d + 1][lr] = vv.v[1];
            Vt[d + 2][lr] = vv.v[2];
            Vt[d + 3][lr] = vv.v[3];
        }
        __syncthreads();

        // ---- S^T = K.Q^T: (s = i*16+quad*4+r, t = tb+jt*16+fr)
#pragma unroll
        for (int i = 0; i < 4; ++i) {
            short8 ka0 = *(const short8*)&Ks[i * 16 + fr][quad * 8];
            short8 ka1 = *(const short8*)&Ks[i * 16 + fr][32 + quad * 8];
#pragma unroll
            for (int jt = 0; jt < 2; ++jt) {
                f32x4 acc = {};
                acc = __builtin_amdgcn_mfma_f32_16x16x32_bf16(ka0, qf[jt][0], acc, 0, 0, 0);
                acc = __builtin_amdgcn_mfma_f32_16x16x32_bf16(ka1, qf[jt][1], acc, 0, 0, 0);
                unsigned u0 = __float_as_uint(__expf(acc[0]));
                unsigned u1 = __float_as_uint(__expf(acc[1]));
                unsigned u2 = __float_as_uint(__expf(acc[2]));
                unsigned u3 = __float_as_uint(__expf(acc[3]));
                lsum += __uint_as_float(u0 & 0xffff0000u);
                lsum += __uint_as_float(u1 & 0xffff0000u);
                lsum += __uint_as_float(u2 & 0xffff0000u);
                lsum += __uint_as_float(u3 & 0xffff0000u);
                uint2 pk;
                pk.x = (u0 >> 16) | (u1 & 0xffff0000u);
                pk.y = (u2 >> 16) | (u3 & 0xffff0000u);
                *(uint2*)&Ps[tb + jt * 16 + fr][i * 16 + quad * 4] = pk;
            }
        }
        // no barrier: each wave reads back only its own Ps rows

        // ---- O^T += V^T.P: (d = jd*16+quad*4+r, t = tb+jt*16+fr)
        short8 pb[2][2];
#pragma unroll
        for (int jt = 0; jt < 2; ++jt)
#pragma unroll
            for (int kh = 0; kh < 2; ++kh)
                pb[jt][kh] = *(const short8*)&Ps[tb + jt * 16 + fr][kh * 32 + quad * 8];
#pragma unroll
        for (int jd = 0; jd < 4; ++jd) {
            short8 va0 = *(const short8*)&Vt[jd * 16 + fr][quad * 8];
            short8 va1 = *(const short8*)&Vt[jd * 16 + fr][32 + quad * 8];
#pragma unroll
            for (int jt = 0; jt < 2; ++jt) {
                oaccT[jd][jt] = __builtin_amdgcn_mfma_f32_16x16x32_bf16(va0, pb[jt][0], oaccT[jd][jt], 0, 0, 0);
                oaccT[jd][jt] = __builtin_amdgcn_mfma_f32_16x16x32_bf16(va1, pb[jt][1], oaccT[jd][jt], 0, 0, 0);
            }
        }
    }

    // ---- epilogue: O^T[d][t] -> part[chunk][t][h*64+d], bf16, b64 stores ----
    short* pc = part + (size_t)chunk * TLEN * DIM;
#pragma unroll
    for (int jt = 0; jt < 2; ++jt)
#pragma unroll
        for (int jd = 0; jd < 4; ++jd) {
            unsigned u0 = bf16_rtne_bits(oaccT[jd][jt][0]);
            unsigned u1 = bf16_rtne_bits(oaccT[jd][jt][1]);
            unsigned u2 = bf16_rtne_bits(oaccT[jd][jt][2]);
            unsigned u3 = bf16_rtne_bits(oaccT[jd][jt][3]);
            uint2 pk;
            pk.x = u0 | (u1 << 16);
            pk.y = u2 | (u3 << 16);
            *(uint2*)(pc + (size_t)(t0 + tb + jt * 16 + fr) * DIM + h * HDIM + jd * 16 + quad * 4) = pk;
        }

    // ---- block-reduce lsum, one atomic per block ----
    red[tid] = lsum;
    __syncthreads();
    for (int off = 128; off > 0; off >>= 1) {
        if (tid < off) red[tid] += red[tid + off];
        __syncthreads();
    }
    if (tid == 0) atomicAdd(&g_Lsum[h], red[0]);
}

extern "C" void kernel_launch(void* const* d_in, const int* in_sizes, int n_in,
                              void* d_out, int out_size, void* d_ws, size_t ws_size,
                              hipStream_t stream)
{
    const float* x     = (const float*)d_in[0];   // [4096, 1024]
    const float* W_in  = (const float*)d_in[1];   // [3072, 1024]
    const float* W_out = (const float*)d_in[2];   // [1024, 1024]
    float* out = (float*)d_out;                   // [4096, 1024] fp32

    char* ws = (char*)d_ws;
    short* xb    = (short*)(ws);                   //  8 MiB @ 0   (later: attnb)
    short* wib   = (short*)(ws + (8u << 20));      //  6 MiB @ 8M
    short* wob   = (short*)(ws + (14u << 20));     //  2 MiB @ 14M
    short* qkvb  = (short*)(ws + (16u << 20));     // 24 MiB @ 16M
    short* part  = (short*)(ws + (40u << 20));     // 16 MiB @ 40M (2 chunks x 8 MiB)
    short* attnb = xb;                             // reuse dead xb region
    // total: 56 MiB (< proven-safe 64 MiB)

    zeroL<<<1, 64, 0, stream>>>();

    conv_bf16<<<(TLEN * DIM / 4 + 255) / 256, 256, 0, stream>>>(x, xb, TLEN * DIM / 4);
    conv_bf16<<<(QKV_COLS * DIM / 4 + 255) / 256, 256, 0, stream>>>(W_in, wib, QKV_COLS * DIM / 4);

    // qkv = x @ W_in^T  (bf16 MFMA; Q columns pre-scaled by 0.125)
    gemm_bt<true, true><<<dim3(TLEN / 128, QKV_COLS / 128), 256, 0, stream>>>(
        xb, wib, qkvb, TLEN, QKV_COLS, DIM);

    attn_mfma<<<dim3(TLEN / 128, NHEAD, NCHUNK), 256, 0, stream>>>(qkvb, part);

    recipL<<<1, 64, 0, stream>>>();
    conv_wout<<<(DIM * DIM / 4 + 255) / 256, 256, 0, stream>>>(W_out, wob);

    combine<<<(TLEN * DIM / 4 + 255) / 256, 256, 0, stream>>>(
        part, part + (size_t)TLEN * DIM, attnb, TLEN * DIM / 4);

    // out = attn' @ (W_out/L)^T  (bf16 MFMA, fp32 out)
    gemm_bt<false, false><<<dim3(TLEN / 128, DIM / 128), 256, 0, stream>>>(
        attnb, wob, out, TLEN, DIM, DIM);
}

// Round 10
// 266.228 us; speedup vs baseline: 1.5023x; 1.0221x over previous
//
#include <hip/hip_runtime.h>

#define TLEN 4096
#define DIM 1024
#define NHEAD 16
#define HDIM 64
#define QKV_COLS (3 * DIM)
// 0.125 * log2(e): attention scores computed in exp2 domain (v_exp_f32 is 2^x)
#define QSCALE 0.1803368801111244f
#define NCHUNK 2
#define SCHUNK (TLEN / NCHUNK)

typedef __attribute__((ext_vector_type(8))) short short8;   // 8 bf16 = 4 VGPR (MFMA A/B frag)
typedef __attribute__((ext_vector_type(4))) float f32x4;    // MFMA C/D frag

struct alignas(8) s4 { short v[4]; };

__device__ float g_Lsum[NHEAD];
__device__ float g_recipL[NHEAD];

__global__ void zeroL() {
    if (threadIdx.x < NHEAD) g_Lsum[threadIdx.x] = 0.0f;
}
__global__ void recipL() {
    if (threadIdx.x < NHEAD) g_recipL[threadIdx.x] = 1.0f / g_Lsum[threadIdx.x];
}

__device__ __forceinline__ unsigned bf16_rtne_bits(float x) {
    unsigned u = __float_as_uint(x);
    return (u + 0x7fffu + ((u >> 16) & 1u)) >> 16;
}

// async global->LDS 16B copy (global_load_lds_dwordx4). LDS dest must be
// wave-uniform base + lane*16 at the callsite (our staging layouts are).
__device__ __forceinline__ void cp16(const short* g, short* l) {
    __builtin_amdgcn_global_load_lds(
        (const __attribute__((address_space(1))) unsigned int*)g,
        (__attribute__((address_space(3))) unsigned int*)l,
        16, 0, 0);
}

// fp32 -> bf16 (RTNE), vectorized; n4 = element count / 4.
__global__ __launch_bounds__(256) void conv_bf16(
    const float* __restrict__ src, short* __restrict__ dst, int n4)
{
    int i = blockIdx.x * 256 + threadIdx.x;
    if (i < n4) {
        float4 v = ((const float4*)src)[i];
        s4 o;
        o.v[0] = (short)bf16_rtne_bits(v.x);
        o.v[1] = (short)bf16_rtne_bits(v.y);
        o.v[2] = (short)bf16_rtne_bits(v.z);
        o.v[3] = (short)bf16_rtne_bits(v.w);
        ((s4*)dst)[i] = o;
    }
}

// W_out [1024,1024] -> bf16 with per-head 1/L folded in (k-group = k/64).
__global__ __launch_bounds__(256) void conv_wout(
    const float* __restrict__ src, short* __restrict__ dst)
{
    int i = blockIdx.x * 256 + threadIdx.x;   // over 1024*1024/4
    float s = g_recipL[(i & 255) >> 4];       // k = (i&255)*4; head = k>>6
    float4 v = ((const float4*)src)[i];
    s4 o;
    o.v[0] = (short)bf16_rtne_bits(v.x * s);
    o.v[1] = (short)bf16_rtne_bits(v.y * s);
    o.v[2] = (short)bf16_rtne_bits(v.z * s);
    o.v[3] = (short)bf16_rtne_bits(v.w * s);
    ((s4*)dst)[i] = o;
}

// attnb = bf16(part0 + part1); n4 = elements/4.
__global__ __launch_bounds__(256) void combine(
    const short* __restrict__ p0, const short* __restrict__ p1,
    short* __restrict__ dst, int n4)
{
    int i = blockIdx.x * 256 + threadIdx.x;
    if (i < n4) {
        s4 a = ((const s4*)p0)[i];
        s4 b = ((const s4*)p1)[i];
        s4 o;
#pragma unroll
        for (int m = 0; m < 4; ++m) {
            float fa = __uint_as_float(((unsigned)(unsigned short)a.v[m]) << 16);
            float fb = __uint_as_float(((unsigned)(unsigned short)b.v[m]) << 16);
            o.v[m] = (short)bf16_rtne_bits(fa + fb);
        }
        ((s4*)dst)[i] = o;
    }
}

// C = A @ B^T, bf16 MFMA. 128x128 tile, 4 waves 2x2, BK=32.
// Staging via async global_load_lds width=16 (LDS offset = 16*c, c = wave
// base + lane -> satisfies the wave-uniform-base + lane*16 constraint).
// SCALE_Q: multiply output cols n < DIM by QSCALE (pre-scales Q for attention).
template <bool OUT_BF16, bool SCALE_Q>
__global__ __launch_bounds__(256) void gemm_bt(
    const short* __restrict__ A, const short* __restrict__ B,
    void* __restrict__ Cout, int M, int N, int K)
{
    __shared__ __align__(16) short As[128][32];
    __shared__ __align__(16) short Bs[128][32];
    const int tid  = threadIdx.x;
    const int wv   = tid >> 6, lane = tid & 63;
    const int fr   = lane & 15, quad = lane >> 4;
    const int wm   = (wv >> 1) * 64, wn = (wv & 1) * 64;
    const int m0 = blockIdx.x * 128, n0 = blockIdx.y * 128;

    f32x4 acc[4][4] = {};

    for (int k0 = 0; k0 < K; k0 += 32) {
        __syncthreads();
#pragma unroll
        for (int c = tid; c < 512; c += 256) {
            int row = c >> 2, col = (c & 3) * 8;
            cp16(A + (size_t)(m0 + row) * K + k0 + col, &As[row][col]);
            cp16(B + (size_t)(n0 + row) * K + k0 + col, &Bs[row][col]);
        }
        __syncthreads();   // drains vmcnt (async LDS stores) before reads

        short8 af[4], bfr[4];
#pragma unroll
        for (int i = 0; i < 4; ++i) {
            af[i]  = *(const short8*)&As[wm + i * 16 + fr][quad * 8];
            bfr[i] = *(const short8*)&Bs[wn + i * 16 + fr][quad * 8];
        }
#pragma unroll
        for (int i = 0; i < 4; ++i)
#pragma unroll
            for (int j = 0; j < 4; ++j)
                acc[i][j] = __builtin_amdgcn_mfma_f32_16x16x32_bf16(af[i], bfr[j], acc[i][j], 0, 0, 0);
    }

    const float sc = (SCALE_Q && n0 < DIM) ? QSCALE : 1.0f;
#pragma unroll
    for (int i = 0; i < 4; ++i)
#pragma unroll
        for (int j = 0; j < 4; ++j)
#pragma unroll
            for (int r = 0; r < 4; ++r) {
                size_t off = (size_t)(m0 + wm + i * 16 + quad * 4 + r) * N + n0 + wn + j * 16 + fr;
                float v = acc[i][j][r] * sc;
                if (OUT_BF16)
                    ((short*)Cout)[off] = (short)bf16_rtne_bits(v);
                else
                    ((float*)Cout)[off] = v;
            }
}

// LDS-staged attention (R8 structure) + VALU diet:
//  - scores in exp2 domain (Q pre-scaled by 0.125*log2e) -> bare v_exp_f32
//    via __builtin_amdgcn_exp2f (NOT __exp2f: glibc macro collision, R9)
//  - P trunc-pack via v_perm_b32 (2 insts / 4 values)
//  - per-head L via ones-row MFMA on the P fragments read back from LDS
//    (sums EXACTLY the truncated P used in PV; each quad holds a duplicate
//    copy -> scale 0.25 at the end). Replaces 64 VALU insts/iter with 4 MFMA.
__global__ __launch_bounds__(256) void attn_mfma(
    const short* __restrict__ qkvb, short* __restrict__ part)
{
    __shared__ short Ks[64][72];    // [s][d]
    __shared__ short Vt[64][72];    // [d][s]
    __shared__ short Ps[128][72];   // Q staged here first ([t][d]), then P [t][s]
    __shared__ float red[256];

    const int tid = threadIdx.x;
    const int t0 = blockIdx.x * 128;
    const int h  = blockIdx.y;
    const int chunk = blockIdx.z;
    const int lr  = tid >> 2;          // 0..63
    const int lc4 = (tid & 3) << 2;    // 0,4,8,12
    const int wv   = tid >> 6;
    const int lane = tid & 63;
    const int fr   = lane & 15;
    const int quad = lane >> 4;
    const int tb   = wv * 32;          // wave's t-strip base within the tile

    // ---- stage Q (128x64, already x0.125*log2e) into the Ps region ----
#pragma unroll
    for (int half = 0; half < 128; half += 64)
#pragma unroll
        for (int c0 = 0; c0 < HDIM; c0 += 16) {
            int d = c0 + lc4;
            *(s4*)&Ps[half + lr][d] =
                *(const s4*)(qkvb + (size_t)(t0 + half + lr) * QKV_COLS + h * HDIM + d);
        }
    __syncthreads();

    // Q fragments (B-operand): [t = tb+jt*16+fr][d = kh*32+quad*8 ..]
    short8 qf[2][2];
#pragma unroll
    for (int jt = 0; jt < 2; ++jt)
#pragma unroll
        for (int kh = 0; kh < 2; ++kh)
            qf[jt][kh] = *(const short8*)&Ps[tb + jt * 16 + fr][kh * 32 + quad * 8];

    short8 ones;
#pragma unroll
    for (int m = 0; m < 8; ++m) ones[m] = (short)0x3F80;   // bf16 1.0

    f32x4 oaccT[4][2] = {};   // [jd][jt], O^T[d][t]
    f32x4 racc[2] = {};       // P row sums per jt (all 4 regs/quads identical)

    for (int s0 = chunk * SCHUNK; s0 < (chunk + 1) * SCHUNK; s0 += 64) {
        __syncthreads();   // prev-iter readers of Ks/Vt/Ps done (also guards qf preload)
#pragma unroll
        for (int c0 = 0; c0 < HDIM; c0 += 16) {
            int d = c0 + lc4;
            *(s4*)&Ks[lr][d] =
                *(const s4*)(qkvb + (size_t)(s0 + lr) * QKV_COLS + DIM + h * HDIM + d);
            s4 vv = *(const s4*)(qkvb + (size_t)(s0 + lr) * QKV_COLS + 2 * DIM + h * HDIM + d);
            Vt[d + 0][lr] = vv.v[0];
            Vt[d + 1][lr] = vv.v[1];
            Vt[d + 2][lr] = vv.v[2];
            Vt[d + 3][lr] = vv.v[3];
        }
        __syncthreads();

        // ---- S^T = K.Q^T: (s = i*16+quad*4+r, t = tb+jt*16+fr)
#pragma unroll
        for (int i = 0; i < 4; ++i) {
            short8 ka0 = *(const short8*)&Ks[i * 16 + fr][quad * 8];
            short8 ka1 = *(const short8*)&Ks[i * 16 + fr][32 + quad * 8];
#pragma unroll
            for (int jt = 0; jt < 2; ++jt) {
                f32x4 acc = {};
                acc = __builtin_amdgcn_mfma_f32_16x16x32_bf16(ka0, qf[jt][0], acc, 0, 0, 0);
                acc = __builtin_amdgcn_mfma_f32_16x16x32_bf16(ka1, qf[jt][1], acc, 0, 0, 0);
                unsigned u0 = __float_as_uint(__builtin_amdgcn_exp2f(acc[0]));
                unsigned u1 = __float_as_uint(__builtin_amdgcn_exp2f(acc[1]));
                unsigned u2 = __float_as_uint(__builtin_amdgcn_exp2f(acc[2]));
                unsigned u3 = __float_as_uint(__builtin_amdgcn_exp2f(acc[3]));
                uint2 pk;   // trunc-to-bf16 pack: [u0.hi, u1.hi], [u2.hi, u3.hi]
                pk.x = __builtin_amdgcn_perm(u1, u0, 0x07060302);
                pk.y = __builtin_amdgcn_perm(u3, u2, 0x07060302);
                *(uint2*)&Ps[tb + jt * 16 + fr][i * 16 + quad * 4] = pk;
            }
        }
        // no barrier: each wave reads back only its own Ps rows

        // ---- O^T += V^T.P: (d = jd*16+quad*4+r, t = tb+jt*16+fr)
        short8 pb[2][2];
#pragma unroll
        for (int jt = 0; jt < 2; ++jt)
#pragma unroll
            for (int kh = 0; kh < 2; ++kh)
                pb[jt][kh] = *(const short8*)&Ps[tb + jt * 16 + fr][kh * 32 + quad * 8];

        // P row sums via ones-row MFMA (sums the truncated P exactly)
#pragma unroll
        for (int jt = 0; jt < 2; ++jt) {
            racc[jt] = __builtin_amdgcn_mfma_f32_16x16x32_bf16(ones, pb[jt][0], racc[jt], 0, 0, 0);
            racc[jt] = __builtin_amdgcn_mfma_f32_16x16x32_bf16(ones, pb[jt][1], racc[jt], 0, 0, 0);
        }
#pragma unroll
        for (int jd = 0; jd < 4; ++jd) {
            short8 va0 = *(const short8*)&Vt[jd * 16 + fr][quad * 8];
            short8 va1 = *(const short8*)&Vt[jd * 16 + fr][32 + quad * 8];
#pragma unroll
            for (int jt = 0; jt < 2; ++jt) {
                oaccT[jd][jt] = __builtin_amdgcn_mfma_f32_16x16x32_bf16(va0, pb[jt][0], oaccT[jd][jt], 0, 0, 0);
                oaccT[jd][jt] = __builtin_amdgcn_mfma_f32_16x16x32_bf16(va1, pb[jt][1], oaccT[jd][jt], 0, 0, 0);
            }
        }
    }

    // ---- epilogue: O^T[d][t] -> part[chunk][t][h*64+d], bf16, b64 stores ----
    short* pc = part + (size_t)chunk * TLEN * DIM;
#pragma unroll
    for (int jt = 0; jt < 2; ++jt)
#pragma unroll
        for (int jd = 0; jd < 4; ++jd) {
            unsigned u0 = bf16_rtne_bits(oaccT[jd][jt][0]);
            unsigned u1 = bf16_rtne_bits(oaccT[jd][jt][1]);
            unsigned u2 = bf16_rtne_bits(oaccT[jd][jt][2]);
            unsigned u3 = bf16_rtne_bits(oaccT[jd][jt][3]);
            uint2 pk;
            pk.x = u0 | (u1 << 16);
            pk.y = u2 | (u3 << 16);
            *(uint2*)(pc + (size_t)(t0 + tb + jt * 16 + fr) * DIM + h * HDIM + jd * 16 + quad * 4) = pk;
        }

    // ---- block-reduce L, one atomic per block ----
    // racc rows are quad-duplicated (4 copies per t) -> scale by 0.25.
    red[tid] = (racc[0][0] + racc[1][0]) * 0.25f;
    __syncthreads();
    for (int off = 128; off > 0; off >>= 1) {
        if (tid < off) red[tid] += red[tid + off];
        __syncthreads();
    }
    if (tid == 0) atomicAdd(&g_Lsum[h], red[0]);
}

extern "C" void kernel_launch(void* const* d_in, const int* in_sizes, int n_in,
                              void* d_out, int out_size, void* d_ws, size_t ws_size,
                              hipStream_t stream)
{
    const float* x     = (const float*)d_in[0];   // [4096, 1024]
    const float* W_in  = (const float*)d_in[1];   // [3072, 1024]
    const float* W_out = (const float*)d_in[2];   // [1024, 1024]
    float* out = (float*)d_out;                   // [4096, 1024] fp32

    char* ws = (char*)d_ws;
    short* xb    = (short*)(ws);                   //  8 MiB @ 0   (later: attnb)
    short* wib   = (short*)(ws + (8u << 20));      //  6 MiB @ 8M
    short* wob   = (short*)(ws + (14u << 20));     //  2 MiB @ 14M
    short* qkvb  = (short*)(ws + (16u << 20));     // 24 MiB @ 16M
    short* part  = (short*)(ws + (40u << 20));     // 16 MiB @ 40M (2 chunks x 8 MiB)
    short* attnb = xb;                             // reuse dead xb region
    // total: 56 MiB (< proven-safe 64 MiB)

    zeroL<<<1, 64, 0, stream>>>();

    conv_bf16<<<(TLEN * DIM / 4 + 255) / 256, 256, 0, stream>>>(x, xb, TLEN * DIM / 4);
    conv_bf16<<<(QKV_COLS * DIM / 4 + 255) / 256, 256, 0, stream>>>(W_in, wib, QKV_COLS * DIM / 4);

    // qkv = x @ W_in^T  (bf16 MFMA; Q columns pre-scaled by 0.125*log2e)
    gemm_bt<true, true><<<dim3(TLEN / 128, QKV_COLS / 128), 256, 0, stream>>>(
        xb, wib, qkvb, TLEN, QKV_COLS, DIM);

    attn_mfma<<<dim3(TLEN / 128, NHEAD, NCHUNK), 256, 0, stream>>>(qkvb, part);

    recipL<<<1, 64, 0, stream>>>();
    conv_wout<<<(DIM * DIM / 4 + 255) / 256, 256, 0, stream>>>(W_out, wob);

    combine<<<(TLEN * DIM / 4 + 255) / 256, 256, 0, stream>>>(
        part, part + (size_t)TLEN * DIM, attnb, TLEN * DIM / 4);

    // out = attn' @ (W_out/L)^T  (bf16 MFMA, fp32 out)
    gemm_bt<false, false><<<dim3(TLEN / 128, DIM / 128), 256, 0, stream>>>(
        attnb, wob, out, TLEN, DIM, DIM);
}

// Round 11
// 253.975 us; speedup vs baseline: 1.5748x; 1.0482x over previous
//
#include <hip/hip_runtime.h>

#define TLEN 4096
#define DIM 1024
#define NHEAD 16
#define HDIM 64
#define QKV_COLS (3 * DIM)
// 0.125 * log2(e): attention scores computed in exp2 domain (v_exp_f32 is 2^x)
#define QSCALE 0.1803368801111244f
#define NCHUNK 2
#define SCHUNK (TLEN / NCHUNK)

typedef __attribute__((ext_vector_type(8))) short short8;   // 8 bf16 = 4 VGPR (MFMA A/B frag)
typedef __attribute__((ext_vector_type(4))) float f32x4;    // MFMA C/D frag

struct alignas(8) s4 { short v[4]; };

__device__ float g_Lsum[NHEAD];
__device__ float g_recipL[NHEAD];

__global__ void zeroL() {
    if (threadIdx.x < NHEAD) g_Lsum[threadIdx.x] = 0.0f;
}
__global__ void recipL() {
    if (threadIdx.x < NHEAD) g_recipL[threadIdx.x] = 1.0f / g_Lsum[threadIdx.x];
}

__device__ __forceinline__ unsigned bf16_rtne_bits(float x) {
    unsigned u = __float_as_uint(x);
    return (u + 0x7fffu + ((u >> 16) & 1u)) >> 16;
}

// async global->LDS 16B copy (global_load_lds_dwordx4). LDS dest must be
// wave-uniform base + lane*16 at the callsite (our staging layouts are).
__device__ __forceinline__ void cp16(const short* g, short* l) {
    __builtin_amdgcn_global_load_lds(
        (const __attribute__((address_space(1))) unsigned int*)g,
        (__attribute__((address_space(3))) unsigned int*)l,
        16, 0, 0);
}

// fp32 -> bf16 (RTNE), vectorized; n4 = element count / 4.
__global__ __launch_bounds__(256) void conv_bf16(
    const float* __restrict__ src, short* __restrict__ dst, int n4)
{
    int i = blockIdx.x * 256 + threadIdx.x;
    if (i < n4) {
        float4 v = ((const float4*)src)[i];
        s4 o;
        o.v[0] = (short)bf16_rtne_bits(v.x);
        o.v[1] = (short)bf16_rtne_bits(v.y);
        o.v[2] = (short)bf16_rtne_bits(v.z);
        o.v[3] = (short)bf16_rtne_bits(v.w);
        ((s4*)dst)[i] = o;
    }
}

// W_out [1024,1024] -> bf16 with per-head 1/L folded in (k-group = k/64).
__global__ __launch_bounds__(256) void conv_wout(
    const float* __restrict__ src, short* __restrict__ dst)
{
    int i = blockIdx.x * 256 + threadIdx.x;   // over 1024*1024/4
    float s = g_recipL[(i & 255) >> 4];       // k = (i&255)*4; head = k>>6
    float4 v = ((const float4*)src)[i];
    s4 o;
    o.v[0] = (short)bf16_rtne_bits(v.x * s);
    o.v[1] = (short)bf16_rtne_bits(v.y * s);
    o.v[2] = (short)bf16_rtne_bits(v.z * s);
    o.v[3] = (short)bf16_rtne_bits(v.w * s);
    ((s4*)dst)[i] = o;
}

// attnb = bf16(part0 + part1); n4 = elements/4.
__global__ __launch_bounds__(256) void combine(
    const short* __restrict__ p0, const short* __restrict__ p1,
    short* __restrict__ dst, int n4)
{
    int i = blockIdx.x * 256 + threadIdx.x;
    if (i < n4) {
        s4 a = ((const s4*)p0)[i];
        s4 b = ((const s4*)p1)[i];
        s4 o;
#pragma unroll
        for (int m = 0; m < 4; ++m) {
            float fa = __uint_as_float(((unsigned)(unsigned short)a.v[m]) << 16);
            float fb = __uint_as_float(((unsigned)(unsigned short)b.v[m]) << 16);
            o.v[m] = (short)bf16_rtne_bits(fa + fb);
        }
        ((s4*)dst)[i] = o;
    }
}

// C = A @ B^T, bf16 MFMA. 128x128 tile, 4 waves 2x2, BK=32.
// Staging via async global_load_lds width=16.
// QKV_MODE: bf16 out; Q cols (n<DIM) scaled by QSCALE; V cols (n>=2*DIM)
//   written TRANSPOSED to Vout[d_global][t] as packed uint2 (lane owns 4
//   consecutive m=t -> free vectorized transposed store).
// else: fp32 out to Cout.
template <bool QKV_MODE>
__global__ __launch_bounds__(256) void gemm_bt(
    const short* __restrict__ A, const short* __restrict__ B,
    void* __restrict__ Cout, short* __restrict__ Vout, int M, int N, int K)
{
    __shared__ __align__(16) short As[128][32];
    __shared__ __align__(16) short Bs[128][32];
    const int tid  = threadIdx.x;
    const int wv   = tid >> 6, lane = tid & 63;
    const int fr   = lane & 15, quad = lane >> 4;
    const int wm   = (wv >> 1) * 64, wn = (wv & 1) * 64;
    const int m0 = blockIdx.x * 128, n0 = blockIdx.y * 128;

    f32x4 acc[4][4] = {};

    for (int k0 = 0; k0 < K; k0 += 32) {
        __syncthreads();
#pragma unroll
        for (int c = tid; c < 512; c += 256) {
            int row = c >> 2, col = (c & 3) * 8;
            cp16(A + (size_t)(m0 + row) * K + k0 + col, &As[row][col]);
            cp16(B + (size_t)(n0 + row) * K + k0 + col, &Bs[row][col]);
        }
        __syncthreads();   // drains vmcnt (async LDS stores) before reads

        short8 af[4], bfr[4];
#pragma unroll
        for (int i = 0; i < 4; ++i) {
            af[i]  = *(const short8*)&As[wm + i * 16 + fr][quad * 8];
            bfr[i] = *(const short8*)&Bs[wn + i * 16 + fr][quad * 8];
        }
#pragma unroll
        for (int i = 0; i < 4; ++i)
#pragma unroll
            for (int j = 0; j < 4; ++j)
                acc[i][j] = __builtin_amdgcn_mfma_f32_16x16x32_bf16(af[i], bfr[j], acc[i][j], 0, 0, 0);
    }

    if (QKV_MODE && n0 >= 2 * DIM) {
        // V tile: write V^T[d_global][t], packed 4 consecutive t per lane
#pragma unroll
        for (int i = 0; i < 4; ++i)
#pragma unroll
            for (int j = 0; j < 4; ++j) {
                int n = n0 - 2 * DIM + wn + j * 16 + fr;        // d_global
                int m = m0 + wm + i * 16 + quad * 4;            // t base
                unsigned u0 = bf16_rtne_bits(acc[i][j][0]);
                unsigned u1 = bf16_rtne_bits(acc[i][j][1]);
                unsigned u2 = bf16_rtne_bits(acc[i][j][2]);
                unsigned u3 = bf16_rtne_bits(acc[i][j][3]);
                uint2 pk;
                pk.x = u0 | (u1 << 16);
                pk.y = u2 | (u3 << 16);
                *(uint2*)(Vout + (size_t)n * TLEN + m) = pk;
            }
    } else if (QKV_MODE) {
        const float sc = (n0 < DIM) ? QSCALE : 1.0f;
#pragma unroll
        for (int i = 0; i < 4; ++i)
#pragma unroll
            for (int j = 0; j < 4; ++j)
#pragma unroll
                for (int r = 0; r < 4; ++r) {
                    size_t off = (size_t)(m0 + wm + i * 16 + quad * 4 + r) * N + n0 + wn + j * 16 + fr;
                    ((short*)Cout)[off] = (short)bf16_rtne_bits(acc[i][j][r] * sc);
                }
    } else {
#pragma unroll
        for (int i = 0; i < 4; ++i)
#pragma unroll
            for (int j = 0; j < 4; ++j)
#pragma unroll
                for (int r = 0; r < 4; ++r) {
                    size_t off = (size_t)(m0 + wm + i * 16 + quad * 4 + r) * N + n0 + wn + j * 16 + fr;
                    ((float*)Cout)[off] = acc[i][j][r];
                }
    }
}

// LDS-staged attention. V^T comes pre-transposed from global (vtb) -> the
// 16 scalar conflicted ds_write_u16/thread/iter of R10 are GONE; K/V/Q
// staging is all b128 loads + b128 LDS writes.
//  - scores in exp2 domain (Q pre-scaled by 0.125*log2e) -> v_exp_f32
//  - P trunc-pack via v_perm_b32; per-head L via ones-row MFMA (quad-dup/4)
__global__ __launch_bounds__(256) void attn_mfma(
    const short* __restrict__ qkvb, const short* __restrict__ vtb,
    short* __restrict__ part)
{
    __shared__ short Ks[64][72];    // [s][d]
    __shared__ short Vt[64][72];    // [d][s]
    __shared__ short Ps[128][72];   // Q staged here first ([t][d]), then P [t][s]
    __shared__ float red[256];

    const int tid = threadIdx.x;
    const int t0 = blockIdx.x * 128;
    const int h  = blockIdx.y;
    const int chunk = blockIdx.z;
    const int srow = tid >> 2;          // 0..63 staging row
    const int sch  = (tid & 3) * 16;    // 0,16,32,48 staging col chunk
    const int wv   = tid >> 6;
    const int lane = tid & 63;
    const int fr   = lane & 15;
    const int quad = lane >> 4;
    const int tb   = wv * 32;           // wave's t-strip base within the tile

    // ---- stage Q (128x64, already x0.125*log2e), b128 pairs ----
#pragma unroll
    for (int half = 0; half < 128; half += 64) {
        const short* src = qkvb + (size_t)(t0 + half + srow) * QKV_COLS + h * HDIM + sch;
        uint4 a = *(const uint4*)(src);
        uint4 b = *(const uint4*)(src + 8);
        *(uint4*)&Ps[half + srow][sch]     = a;
        *(uint4*)&Ps[half + srow][sch + 8] = b;
    }
    __syncthreads();

    // Q fragments (B-operand): [t = tb+jt*16+fr][d = kh*32+quad*8 ..]
    short8 qf[2][2];
#pragma unroll
    for (int jt = 0; jt < 2; ++jt)
#pragma unroll
        for (int kh = 0; kh < 2; ++kh)
            qf[jt][kh] = *(const short8*)&Ps[tb + jt * 16 + fr][kh * 32 + quad * 8];

    short8 ones;
#pragma unroll
    for (int m = 0; m < 8; ++m) ones[m] = (short)0x3F80;   // bf16 1.0

    f32x4 oaccT[4][2] = {};   // [jd][jt], O^T[d][t]
    f32x4 racc[2] = {};       // P row sums per jt (quad-duplicated)

    for (int s0 = chunk * SCHUNK; s0 < (chunk + 1) * SCHUNK; s0 += 64) {
        __syncthreads();   // prev-iter readers of Ks/Vt/Ps done (also guards qf preload)
        {
            const short* ksrc = qkvb + (size_t)(s0 + srow) * QKV_COLS + DIM + h * HDIM + sch;
            uint4 ka = *(const uint4*)(ksrc);
            uint4 kb = *(const uint4*)(ksrc + 8);
            const short* vsrc = vtb + (size_t)(h * HDIM + srow) * TLEN + s0 + sch;
            uint4 va = *(const uint4*)(vsrc);
            uint4 vb = *(const uint4*)(vsrc + 8);
            *(uint4*)&Ks[srow][sch]     = ka;
            *(uint4*)&Ks[srow][sch + 8] = kb;
            *(uint4*)&Vt[srow][sch]     = va;
            *(uint4*)&Vt[srow][sch + 8] = vb;
        }
        __syncthreads();

        // ---- S^T = K.Q^T: (s = i*16+quad*4+r, t = tb+jt*16+fr)
#pragma unroll
        for (int i = 0; i < 4; ++i) {
            short8 ka0 = *(const short8*)&Ks[i * 16 + fr][quad * 8];
            short8 ka1 = *(const short8*)&Ks[i * 16 + fr][32 + quad * 8];
#pragma unroll
            for (int jt = 0; jt < 2; ++jt) {
                f32x4 acc = {};
                acc = __builtin_amdgcn_mfma_f32_16x16x32_bf16(ka0, qf[jt][0], acc, 0, 0, 0);
                acc = __builtin_amdgcn_mfma_f32_16x16x32_bf16(ka1, qf[jt][1], acc, 0, 0, 0);
                unsigned u0 = __float_as_uint(__builtin_amdgcn_exp2f(acc[0]));
                unsigned u1 = __float_as_uint(__builtin_amdgcn_exp2f(acc[1]));
                unsigned u2 = __float_as_uint(__builtin_amdgcn_exp2f(acc[2]));
                unsigned u3 = __float_as_uint(__builtin_amdgcn_exp2f(acc[3]));
                uint2 pk;   // trunc-to-bf16 pack: [u0.hi, u1.hi], [u2.hi, u3.hi]
                pk.x = __builtin_amdgcn_perm(u1, u0, 0x07060302);
                pk.y = __builtin_amdgcn_perm(u3, u2, 0x07060302);
                *(uint2*)&Ps[tb + jt * 16 + fr][i * 16 + quad * 4] = pk;
            }
        }
        // no barrier: each wave reads back only its own Ps rows

        // ---- O^T += V^T.P: (d = jd*16+quad*4+r, t = tb+jt*16+fr)
        short8 pb[2][2];
#pragma unroll
        for (int jt = 0; jt < 2; ++jt)
#pragma unroll
            for (int kh = 0; kh < 2; ++kh)
                pb[jt][kh] = *(const short8*)&Ps[tb + jt * 16 + fr][kh * 32 + quad * 8];

        // P row sums via ones-row MFMA (sums the truncated P exactly)
#pragma unroll
        for (int jt = 0; jt < 2; ++jt) {
            racc[jt] = __builtin_amdgcn_mfma_f32_16x16x32_bf16(ones, pb[jt][0], racc[jt], 0, 0, 0);
            racc[jt] = __builtin_amdgcn_mfma_f32_16x16x32_bf16(ones, pb[jt][1], racc[jt], 0, 0, 0);
        }
#pragma unroll
        for (int jd = 0; jd < 4; ++jd) {
            short8 va0 = *(const short8*)&Vt[jd * 16 + fr][quad * 8];
            short8 va1 = *(const short8*)&Vt[jd * 16 + fr][32 + quad * 8];
#pragma unroll
            for (int jt = 0; jt < 2; ++jt) {
                oaccT[jd][jt] = __builtin_amdgcn_mfma_f32_16x16x32_bf16(va0, pb[jt][0], oaccT[jd][jt], 0, 0, 0);
                oaccT[jd][jt] = __builtin_amdgcn_mfma_f32_16x16x32_bf16(va1, pb[jt][1], oaccT[jd][jt], 0, 0, 0);
            }
        }
    }

    // ---- epilogue: O^T[d][t] -> part[chunk][t][h*64+d], bf16, b64 stores ----
    short* pc = part + (size_t)chunk * TLEN * DIM;
#pragma unroll
    for (int jt = 0; jt < 2; ++jt)
#pragma unroll
        for (int jd = 0; jd < 4; ++jd) {
            unsigned u0 = bf16_rtne_bits(oaccT[jd][jt][0]);
            unsigned u1 = bf16_rtne_bits(oaccT[jd][jt][1]);
            unsigned u2 = bf16_rtne_bits(oaccT[jd][jt][2]);
            unsigned u3 = bf16_rtne_bits(oaccT[jd][jt][3]);
            uint2 pk;
            pk.x = u0 | (u1 << 16);
            pk.y = u2 | (u3 << 16);
            *(uint2*)(pc + (size_t)(t0 + tb + jt * 16 + fr) * DIM + h * HDIM + jd * 16 + quad * 4) = pk;
        }

    // ---- block-reduce L, one atomic per block (racc quad-duplicated /4) ----
    red[tid] = (racc[0][0] + racc[1][0]) * 0.25f;
    __syncthreads();
    for (int off = 128; off > 0; off >>= 1) {
        if (tid < off) red[tid] += red[tid + off];
        __syncthreads();
    }
    if (tid == 0) atomicAdd(&g_Lsum[h], red[0]);
}

extern "C" void kernel_launch(void* const* d_in, const int* in_sizes, int n_in,
                              void* d_out, int out_size, void* d_ws, size_t ws_size,
                              hipStream_t stream)
{
    const float* x     = (const float*)d_in[0];   // [4096, 1024]
    const float* W_in  = (const float*)d_in[1];   // [3072, 1024]
    const float* W_out = (const float*)d_in[2];   // [1024, 1024]
    float* out = (float*)d_out;                   // [4096, 1024] fp32

    char* ws = (char*)d_ws;
    short* xb    = (short*)(ws);                   //  8 MiB @ 0   (later: attnb)
    short* wib   = (short*)(ws + (8u << 20));      //  6 MiB @ 8M
    short* wob   = (short*)(ws + (14u << 20));     //  2 MiB @ 14M
    short* qkvb  = (short*)(ws + (16u << 20));     // 24 MiB @ 16M (V region unused)
    short* vtb   = (short*)(ws + (40u << 20));     //  8 MiB @ 40M (V^T [d_global][s])
    short* part  = (short*)(ws + (48u << 20));     // 16 MiB @ 48M (2 chunks x 8 MiB)
    short* attnb = xb;                             // reuse dead xb region
    // total: exactly 64 MiB (proven safe in R3/R4)

    zeroL<<<1, 64, 0, stream>>>();

    conv_bf16<<<(TLEN * DIM / 4 + 255) / 256, 256, 0, stream>>>(x, xb, TLEN * DIM / 4);
    conv_bf16<<<(QKV_COLS * DIM / 4 + 255) / 256, 256, 0, stream>>>(W_in, wib, QKV_COLS * DIM / 4);

    // qkv = x @ W_in^T  (bf16 MFMA; Q cols x0.125*log2e; V cols -> vtb transposed)
    gemm_bt<true><<<dim3(TLEN / 128, QKV_COLS / 128), 256, 0, stream>>>(
        xb, wib, qkvb, vtb, TLEN, QKV_COLS, DIM);

    attn_mfma<<<dim3(TLEN / 128, NHEAD, NCHUNK), 256, 0, stream>>>(qkvb, vtb, part);

    recipL<<<1, 64, 0, stream>>>();
    conv_wout<<<(DIM * DIM / 4 + 255) / 256, 256, 0, stream>>>(W_out, wob);

    combine<<<(TLEN * DIM / 4 + 255) / 256, 256, 0, stream>>>(
        part, part + (size_t)TLEN * DIM, attnb, TLEN * DIM / 4);

    // out = attn' @ (W_out/L)^T  (bf16 MFMA, fp32 out)
    gemm_bt<false><<<dim3(TLEN / 128, DIM / 128), 256, 0, stream>>>(
        attnb, wob, out, nullptr, TLEN, DIM, DIM);
}